// Round 1
// baseline (194.980 us; speedup 1.0000x reference)
//
#include <hip/hip_runtime.h>
#include <stdint.h>

#define N_IMG 256
#define HW 196
#define CDIM 512

#define F_EPS_POS 0.65f
#define F_EPS_NEG 0.40f
#define F_INV_TAU (1.0f/0.03f)
#define F_TEMP 0.07f

typedef __attribute__((ext_vector_type(8))) short bf16x8;
typedef __attribute__((ext_vector_type(8))) unsigned short u16x8;
typedef __attribute__((ext_vector_type(4))) float f32x4;

__device__ __forceinline__ unsigned short f2bf(float x){
    unsigned int u = __float_as_uint(x);
    u = (u + 0x7FFFu + ((u >> 16) & 1u)) >> 16;
    return (unsigned short)u;
}
__device__ __forceinline__ float sigm(float x){ return 1.0f/(1.0f + __expf(-x)); }

// ---------------- kernel 1: audio L2-normalize -> bf16 ----------------
__global__ void audio_norm_k(const float* __restrict__ audio,
                             unsigned short* __restrict__ abf){
    int k = blockIdx.x, t = threadIdx.x;
    __shared__ float red[256];
    float v0 = audio[k*CDIM + t];
    float v1 = audio[k*CDIM + t + 256];
    red[t] = v0*v0 + v1*v1;
    __syncthreads();
    for (int s = 128; s > 0; s >>= 1){
        if (t < s) red[t] += red[t+s];
        __syncthreads();
    }
    float rrt = 1.0f / sqrtf(red[0]);
    abf[k*CDIM + t]       = f2bf(v0*rrt);
    abf[k*CDIM + t + 256] = f2bf(v1*rrt);
}

// ---------------- kernel 2: main GEMM + weighted reductions ----------------
// grid = 1024: XCD-chunk swizzle, then n = w>>2, k-quarter = w&3 (64 k each).
// B (audio) fragments: 16 x bf16x8 = 64 VGPRs/lane -> ~120 regs total ->
// 4 blocks/CU (16 waves/CU) with __launch_bounds__(256,4). 1024 blocks =
// exactly one fully-resident pass on 256 CUs.
// Staging loads are per-instruction coalesced (16-lane contiguous runs).
__global__ __launch_bounds__(256, 4)
void main_k(const float* __restrict__ frame,
            const unsigned short* __restrict__ abf,
            float* __restrict__ num, float* __restrict__ den,
            float* __restrict__ hnum, float* __restrict__ hden){
    __shared__ unsigned short fT[2][16*520];   // 520 stride: bank-friendly b128
    __shared__ float rnormS[2][16];

    const int t = threadIdx.x;
    // XCD-chunk swizzle: all 4 k-quarter blocks of one n land on one XCD's L2.
    const int w  = ((blockIdx.x & 7) << 7) + (blockIdx.x >> 3);
    const int n  = w >> 2;
    const int k0 = (w & 3) << 6;
    const int lane = t & 63, wid = t >> 6;
    const int col  = lane & 15, quad = lane >> 4;
    const int kg   = k0 + wid*16 + col;

    // ---- B fragments in registers (16 x bf16x8 = 64 VGPRs) ----
    bf16x8 B[16];
    {
        const unsigned short* bp = abf + (size_t)kg*CDIM + quad*8;
        #pragma unroll
        for (int j = 0; j < 16; ++j) B[j] = *(const bf16x8*)(bp + j*32);
    }

    const int r = t >> 4;      // staging row within tile (0..15)
    const int c = t & 15;      // staging column group (8 channels per j-chunk)

    float en = 0.f, ed = 0.f, hn = 0.f, hd = 0.f;

    // coalesced stage loads: instr i -> lanes c=0..15 read float4s 32B apart,
    // pair (i, i^1) covers contiguous 512B per row; 4 rows per wave.
    auto loadT = [&](int pt, float4* v){
        int p = pt*16 + r;
        if (p > HW-1) p = HW-1;               // clamp: pad rows duplicate row 195,
                                              // discarded by prow<HW in epilogue
        const float4* src = (const float4*)(frame + ((size_t)n*HW + p)*CDIM);
        #pragma unroll
        for (int i = 0; i < 8; ++i)
            v[i] = src[(c << 1) + (i & 1) + (i >> 1)*32];
    };
    // convert+write v into buf, compute row rsqrt via 16-lane shuffle
    auto storeT = [&](const float4* v, int buf){
        float ss = 0.f;
        #pragma unroll
        for (int i = 0; i < 8; ++i)
            ss += v[i].x*v[i].x + v[i].y*v[i].y + v[i].z*v[i].z + v[i].w*v[i].w;
        unsigned short* dst = fT[buf] + r*520 + c*8;
        #pragma unroll
        for (int j = 0; j < 4; ++j){          // channels c*8 + j*128 .. +7
            float4 a = v[2*j], b = v[2*j+1];
            u16x8 u = { f2bf(a.x), f2bf(a.y), f2bf(a.z), f2bf(a.w),
                        f2bf(b.x), f2bf(b.y), f2bf(b.z), f2bf(b.w) };
            *(u16x8*)(dst + j*128) = u;
        }
        ss += __shfl_xor(ss, 1, 64);
        ss += __shfl_xor(ss, 2, 64);
        ss += __shfl_xor(ss, 4, 64);
        ss += __shfl_xor(ss, 8, 64);
        if (c == 0)
            rnormS[buf][r] = (ss > 0.f) ? (1.0f/sqrtf(ss)) : 0.f;
    };

    // prologue: tile 0 into buffer 0
    {
        float4 v[8];
        loadT(0, v);
        storeT(v, 0);
    }
    __syncthreads();

    for (int pt = 0; pt < 13; ++pt){
        const int cur = pt & 1, nxt = cur ^ 1;
        const bool hasNext = (pt < 12);

        float4 v[8];
        if (hasNext) loadT(pt + 1, v);       // prefetch: hidden by MFMA phase

        // ---- MFMA phase on buf[cur]: 16 j-steps, single acc chain ----
        const unsigned short* fbase = fT[cur] + col*520 + quad*8;
        f32x4 acc = {0.f,0.f,0.f,0.f};
        #pragma unroll
        for (int j = 0; j < 16; ++j){
            bf16x8 a = *(const bf16x8*)(fbase + j*32);
            acc = __builtin_amdgcn_mfma_f32_16x16x32_bf16(a, B[j], acc, 0, 0, 0);
        }
        f32x4 rn4 = *(const f32x4*)(&rnormS[cur][quad*4]);
        #pragma unroll
        for (int rr = 0; rr < 4; ++rr){
            int prow = pt*16 + quad*4 + rr;
            if (prow < HW){
                float s  = acc[rr] * rn4[rr];
                float wp = sigm((s - F_EPS_POS) * F_INV_TAU);
                en += wp*s; ed += wp;
                if (kg == n){ float wn = 1.f - sigm((s - F_EPS_NEG) * F_INV_TAU); hn += wn*s; hd += wn; }
            }
        }

        if (hasNext) storeT(v, nxt);
        __syncthreads();
    }

    // reduce across quads (rows live in quads; kg identical per quad)
    en += __shfl_xor(en, 16, 64); en += __shfl_xor(en, 32, 64);
    ed += __shfl_xor(ed, 16, 64); ed += __shfl_xor(ed, 32, 64);
    hn += __shfl_xor(hn, 16, 64); hn += __shfl_xor(hn, 32, 64);
    hd += __shfl_xor(hd, 16, 64); hd += __shfl_xor(hd, 32, 64);

    if (quad == 0){
        num[n*N_IMG + kg] = en;  den[n*N_IMG + kg] = ed;
        if (kg == n){ hnum[n] = hn; hden[n] = hd; }
    }
}

// ---------------- kernel 3: per-n Pi_d / Ni_d (parallel over n) ----------------
__global__ void pd_k(const float* __restrict__ num, const float* __restrict__ den,
                     const float* __restrict__ hnum, const float* __restrict__ hden,
                     float* __restrict__ Pi_d, float* __restrict__ Ni_d){
    int nn = blockIdx.x, t = threadIdx.x;
    __shared__ float red[256];
    __shared__ float diagv;
    float ratio = num[nn*N_IMG + t] / den[nn*N_IMG + t];
    if (t == nn) diagv = ratio;
    red[t] = ratio * (t == nn ? -99.f : 1.f);
    __syncthreads();
    for (int s = 128; s > 0; s >>= 1){
        if (t < s) red[t] += red[t+s];
        __syncthreads();
    }
    if (t == 0){
        Pi_d[nn] = F_TEMP * diagv;
        Ni_d[nn] = F_TEMP * (hnum[nn]/hden[nn] + red[0]);
    }
}

// ---------------- kernel 4: broadcast (N,N) log-sum + atomic total ----------------
// loss = (1/N) * sum_{i,j} log(1 + exp(Ni_d[j] - Pi_d[i]))
__global__ void loss_k(const float* __restrict__ Pi_d, const float* __restrict__ Ni_d,
                       float* __restrict__ out){
    int i = blockIdx.x, j = threadIdx.x;
    __shared__ float red[256];
    float x = Ni_d[j] - Pi_d[i];
    red[j] = (x > 20.f) ? x : log1pf(__expf(x));
    __syncthreads();
    for (int s = 128; s > 0; s >>= 1){
        if (j < s) red[j] += red[j+s];
        __syncthreads();
    }
    if (j == 0) atomicAdd(out, red[0] * (1.0f/(float)N_IMG));
}

extern "C" void kernel_launch(void* const* d_in, const int* in_sizes, int n_in,
                              void* d_out, int out_size, void* d_ws, size_t ws_size,
                              hipStream_t stream) {
    const float* frame = (const float*)d_in[0];
    const float* audio = (const float*)d_in[1];
    float* out = (float*)d_out;
    char* ws = (char*)d_ws;

    unsigned short* abf = (unsigned short*)(ws);            // 262144 B
    float* num  = (float*)(ws + 262144);                    // 262144 B
    float* den  = (float*)(ws + 524288);                    // 262144 B
    float* hnum = (float*)(ws + 786432);                    // 1024 B
    float* hden = (float*)(ws + 787456);                    // 1024 B
    float* Pi_d = (float*)(ws + 788480);                    // 1024 B
    float* Ni_d = (float*)(ws + 789504);                    // 1024 B

    hipMemsetAsync(out, 0, sizeof(float), stream);          // capture-legal

    audio_norm_k<<<N_IMG, 256, 0, stream>>>(audio, abf);
    main_k<<<N_IMG*4, 256, 0, stream>>>(frame, abf, num, den, hnum, hden);
    pd_k<<<N_IMG, 256, 0, stream>>>(num, den, hnum, hden, Pi_d, Ni_d);
    loss_k<<<N_IMG, 256, 0, stream>>>(Pi_d, Ni_d, out);
}

// Round 2
// 175.921 us; speedup vs baseline: 1.1083x; 1.1083x over previous
//
#include <hip/hip_runtime.h>
#include <stdint.h>

#define N_IMG 256
#define HW 196
#define CDIM 512

#define F_EPS_POS 0.65f
#define F_EPS_NEG 0.40f
#define F_INV_TAU (1.0f/0.03f)
#define F_TEMP 0.07f

typedef __attribute__((ext_vector_type(8))) short bf16x8;
typedef __attribute__((ext_vector_type(4))) unsigned short u16x4;
typedef __attribute__((ext_vector_type(4))) float f32x4;

__device__ __forceinline__ unsigned short f2bf(float x){
    unsigned int u = __float_as_uint(x);
    u = (u + 0x7FFFu + ((u >> 16) & 1u)) >> 16;
    return (unsigned short)u;
}
__device__ __forceinline__ float sigm(float x){ return 1.0f/(1.0f + __expf(-x)); }

// ---------------- kernel 1: audio L2-normalize -> bf16 ----------------
__global__ void audio_norm_k(const float* __restrict__ audio,
                             unsigned short* __restrict__ abf){
    int k = blockIdx.x, t = threadIdx.x;
    __shared__ float red[256];
    float v0 = audio[k*CDIM + t];
    float v1 = audio[k*CDIM + t + 256];
    red[t] = v0*v0 + v1*v1;
    __syncthreads();
    for (int s = 128; s > 0; s >>= 1){
        if (t < s) red[t] += red[t+s];
        __syncthreads();
    }
    float rrt = 1.0f / sqrtf(red[0]);
    abf[k*CDIM + t]       = f2bf(v0*rrt);
    abf[k*CDIM + t + 256] = f2bf(v1*rrt);
}

// ---------------- kernel 2: main GEMM + weighted reductions ----------------
// grid = 256 (one block per n, exactly 1 block/CU), block = 512 (8 waves).
// k-split 1: each wave holds 32 k-cols of B in regs (2x16 bf16x8 = 128 VGPR),
// 8 waves cover all 256 k -> frame read EXACTLY once from HBM, no reuse needed.
// Staging: wave w owns tile rows 2w,2w+1; every load instr is 64 lanes x 16B
// CONTIGUOUS (1KB = 16 lines minimum) -- fixes round-0's 64-line strided loads.
__global__ __launch_bounds__(512, 2)
void main_k(const float* __restrict__ frame,
            const unsigned short* __restrict__ abf,
            float* __restrict__ num, float* __restrict__ den,
            float* __restrict__ hnum, float* __restrict__ hden){
    __shared__ unsigned short fT[2][16*520];   // 520 stride: conflict-free b128
    __shared__ float rnormS[2][16];

    const int t    = threadIdx.x;
    const int n    = blockIdx.x;
    const int lane = t & 63, wid = t >> 6;     // wid 0..7
    const int col  = lane & 15, quad = lane >> 4;
    const int kg0  = wid*32 + col;             // this wave's k columns
    const int kg1  = kg0 + 16;

    // ---- B fragments in registers (2 x 16 x bf16x8 = 128 VGPRs) ----
    bf16x8 B0[16], B1[16];
    {
        const unsigned short* b0p = abf + (size_t)kg0*CDIM + quad*8;
        const unsigned short* b1p = abf + (size_t)kg1*CDIM + quad*8;
        #pragma unroll
        for (int j = 0; j < 16; ++j){
            B0[j] = *(const bf16x8*)(b0p + j*32);
            B1[j] = *(const bf16x8*)(b1p + j*32);
        }
    }

    const int r0 = 2*wid, r1 = r0 + 1;         // this wave's tile rows

    float en0=0.f, en1=0.f, ed0=0.f, ed1=0.f;
    float hn0=0.f, hn1=0.f, hd0=0.f, hd1=0.f;

    // perfectly coalesced stage loads: each instr = 64 lanes x 16B contiguous
    auto loadT = [&](int pt, float4* v){
        int p0 = pt*16 + r0; if (p0 > HW-1) p0 = HW-1;   // clamp: pad rows dup
        int p1 = pt*16 + r1; if (p1 > HW-1) p1 = HW-1;   // row 195, discarded
        const float4* s0 = (const float4*)(frame + ((size_t)n*HW + p0)*CDIM);
        const float4* s1 = (const float4*)(frame + ((size_t)n*HW + p1)*CDIM);
        v[0] = s0[lane]; v[1] = s0[lane + 64];
        v[2] = s1[lane]; v[3] = s1[lane + 64];
    };
    // convert+write v into buf, full-wave row rsqrt via butterfly shuffle
    auto storeT = [&](const float4* v, int buf){
        float ss0 = v[0].x*v[0].x + v[0].y*v[0].y + v[0].z*v[0].z + v[0].w*v[0].w
                  + v[1].x*v[1].x + v[1].y*v[1].y + v[1].z*v[1].z + v[1].w*v[1].w;
        float ss1 = v[2].x*v[2].x + v[2].y*v[2].y + v[2].z*v[2].z + v[2].w*v[2].w
                  + v[3].x*v[3].x + v[3].y*v[3].y + v[3].z*v[3].z + v[3].w*v[3].w;
        unsigned short* d0 = fT[buf] + r0*520;
        unsigned short* d1 = fT[buf] + r1*520;
        u16x4 u0 = { f2bf(v[0].x), f2bf(v[0].y), f2bf(v[0].z), f2bf(v[0].w) };
        u16x4 u1 = { f2bf(v[1].x), f2bf(v[1].y), f2bf(v[1].z), f2bf(v[1].w) };
        u16x4 u2 = { f2bf(v[2].x), f2bf(v[2].y), f2bf(v[2].z), f2bf(v[2].w) };
        u16x4 u3 = { f2bf(v[3].x), f2bf(v[3].y), f2bf(v[3].z), f2bf(v[3].w) };
        *(u16x4*)(d0 + lane*4)       = u0;
        *(u16x4*)(d0 + 256 + lane*4) = u1;
        *(u16x4*)(d1 + lane*4)       = u2;
        *(u16x4*)(d1 + 256 + lane*4) = u3;
        #pragma unroll
        for (int d = 1; d < 64; d <<= 1){
            ss0 += __shfl_xor(ss0, d, 64);
            ss1 += __shfl_xor(ss1, d, 64);
        }
        if (lane == 0){
            rnormS[buf][r0] = (ss0 > 0.f) ? (1.0f/sqrtf(ss0)) : 0.f;
            rnormS[buf][r1] = (ss1 > 0.f) ? (1.0f/sqrtf(ss1)) : 0.f;
        }
    };

    // prologue: tile 0 into buffer 0
    {
        float4 v[4];
        loadT(0, v);
        storeT(v, 0);
    }
    __syncthreads();

    for (int pt = 0; pt < 13; ++pt){
        const int cur = pt & 1, nxt = cur ^ 1;
        const bool hasNext = (pt < 12);

        float4 v[4];
        if (hasNext) loadT(pt + 1, v);   // prefetch: in flight under MFMA phase

        // ---- MFMA phase on buf[cur]: 16 ds_read shared by 2 MFMA chains ----
        const unsigned short* fbase = fT[cur] + col*520 + quad*8;
        f32x4 acc0 = {0.f,0.f,0.f,0.f};
        f32x4 acc1 = {0.f,0.f,0.f,0.f};
        #pragma unroll
        for (int j = 0; j < 16; ++j){
            bf16x8 a = *(const bf16x8*)(fbase + j*32);
            acc0 = __builtin_amdgcn_mfma_f32_16x16x32_bf16(a, B0[j], acc0, 0, 0, 0);
            acc1 = __builtin_amdgcn_mfma_f32_16x16x32_bf16(a, B1[j], acc1, 0, 0, 0);
        }
        f32x4 rn4 = *(const f32x4*)(&rnormS[cur][quad*4]);
        #pragma unroll
        for (int rr = 0; rr < 4; ++rr){
            int prow = pt*16 + quad*4 + rr;
            if (prow < HW){
                float s0 = acc0[rr] * rn4[rr];
                float s1 = acc1[rr] * rn4[rr];
                float w0 = sigm((s0 - F_EPS_POS) * F_INV_TAU);
                float w1 = sigm((s1 - F_EPS_POS) * F_INV_TAU);
                en0 += w0*s0; ed0 += w0;
                en1 += w1*s1; ed1 += w1;
                if (kg0 == n){ float wn = 1.f - sigm((s0 - F_EPS_NEG) * F_INV_TAU); hn0 += wn*s0; hd0 += wn; }
                if (kg1 == n){ float wn = 1.f - sigm((s1 - F_EPS_NEG) * F_INV_TAU); hn1 += wn*s1; hd1 += wn; }
            }
        }

        if (hasNext) storeT(v, nxt);
        __syncthreads();
    }

    // reduce across quads (rows live in quads; k identical per quad)
    en0 += __shfl_xor(en0, 16, 64); en0 += __shfl_xor(en0, 32, 64);
    ed0 += __shfl_xor(ed0, 16, 64); ed0 += __shfl_xor(ed0, 32, 64);
    en1 += __shfl_xor(en1, 16, 64); en1 += __shfl_xor(en1, 32, 64);
    ed1 += __shfl_xor(ed1, 16, 64); ed1 += __shfl_xor(ed1, 32, 64);
    hn0 += __shfl_xor(hn0, 16, 64); hn0 += __shfl_xor(hn0, 32, 64);
    hd0 += __shfl_xor(hd0, 16, 64); hd0 += __shfl_xor(hd0, 32, 64);
    hn1 += __shfl_xor(hn1, 16, 64); hn1 += __shfl_xor(hn1, 32, 64);
    hd1 += __shfl_xor(hd1, 16, 64); hd1 += __shfl_xor(hd1, 32, 64);

    if (quad == 0){
        num[n*N_IMG + kg0] = en0;  den[n*N_IMG + kg0] = ed0;
        num[n*N_IMG + kg1] = en1;  den[n*N_IMG + kg1] = ed1;
        if (kg0 == n){ hnum[n] = hn0; hden[n] = hd0; }
        if (kg1 == n){ hnum[n] = hn1; hden[n] = hd1; }
    }
}

// ---------------- kernel 3: per-n Pi_d / Ni_d (parallel over n) ----------------
__global__ void pd_k(const float* __restrict__ num, const float* __restrict__ den,
                     const float* __restrict__ hnum, const float* __restrict__ hden,
                     float* __restrict__ Pi_d, float* __restrict__ Ni_d){
    int nn = blockIdx.x, t = threadIdx.x;
    __shared__ float red[256];
    __shared__ float diagv;
    float ratio = num[nn*N_IMG + t] / den[nn*N_IMG + t];
    if (t == nn) diagv = ratio;
    red[t] = ratio * (t == nn ? -99.f : 1.f);
    __syncthreads();
    for (int s = 128; s > 0; s >>= 1){
        if (t < s) red[t] += red[t+s];
        __syncthreads();
    }
    if (t == 0){
        Pi_d[nn] = F_TEMP * diagv;
        Ni_d[nn] = F_TEMP * (hnum[nn]/hden[nn] + red[0]);
    }
}

// ---------------- kernel 4: broadcast (N,N) log-sum + atomic total ----------------
// loss = (1/N) * sum_{i,j} log(1 + exp(Ni_d[j] - Pi_d[i]))
__global__ void loss_k(const float* __restrict__ Pi_d, const float* __restrict__ Ni_d,
                       float* __restrict__ out){
    int i = blockIdx.x, j = threadIdx.x;
    __shared__ float red[256];
    float x = Ni_d[j] - Pi_d[i];
    red[j] = (x > 20.f) ? x : log1pf(__expf(x));
    __syncthreads();
    for (int s = 128; s > 0; s >>= 1){
        if (j < s) red[j] += red[j+s];
        __syncthreads();
    }
    if (j == 0) atomicAdd(out, red[0] * (1.0f/(float)N_IMG));
}

extern "C" void kernel_launch(void* const* d_in, const int* in_sizes, int n_in,
                              void* d_out, int out_size, void* d_ws, size_t ws_size,
                              hipStream_t stream) {
    const float* frame = (const float*)d_in[0];
    const float* audio = (const float*)d_in[1];
    float* out = (float*)d_out;
    char* ws = (char*)d_ws;

    unsigned short* abf = (unsigned short*)(ws);            // 262144 B
    float* num  = (float*)(ws + 262144);                    // 262144 B
    float* den  = (float*)(ws + 524288);                    // 262144 B
    float* hnum = (float*)(ws + 786432);                    // 1024 B
    float* hden = (float*)(ws + 787456);                    // 1024 B
    float* Pi_d = (float*)(ws + 788480);                    // 1024 B
    float* Ni_d = (float*)(ws + 789504);                    // 1024 B

    hipMemsetAsync(out, 0, sizeof(float), stream);          // capture-legal

    audio_norm_k<<<N_IMG, 256, 0, stream>>>(audio, abf);
    main_k<<<N_IMG, 512, 0, stream>>>(frame, abf, num, den, hnum, hden);
    pd_k<<<N_IMG, 256, 0, stream>>>(num, den, hnum, hden, Pi_d, Ni_d);
    loss_k<<<N_IMG, 256, 0, stream>>>(Pi_d, Ni_d, out);
}